// Round 4
// baseline (224.499 us; speedup 1.0000x reference)
//
#include <hip/hip_runtime.h>

// Problem constants: B=32, T=512, F=513, S=3
#define BB 32
#define NN (512 * 513)                    // 262656 elements per (b, source)
#define FLOATS_PER_B (NN * 3)             // 787968 floats per batch slice
#define CHUNKS_PER_B (FLOATS_PER_B / 12)  // 65664 chunks of 12 floats
#define THREADS 256
#define BLOCKS_PER_B 64
#define TPB (BLOCKS_PER_B * THREADS)      // 16384 threads per batch slice
#define MAIN_CHUNKS (4 * TPB)             // 65536 chunks covered by 4/thread
#define TAIL (CHUNKS_PER_B - MAIN_CHUNKS) // 128 leftover chunks

__device__ __forceinline__ void acc_chunk(
        float acc[9],
        const float4& e0, const float4& e1, const float4& e2,
        const float4& t0, const float4& t1, const float4& t2) {
    const float e[12] = {e0.x, e0.y, e0.z, e0.w, e1.x, e1.y,
                         e1.z, e1.w, e2.x, e2.y, e2.z, e2.w};
    const float t[12] = {t0.x, t0.y, t0.z, t0.w, t1.x, t1.y,
                         t1.z, t1.w, t2.x, t2.y, t2.z, t2.w};
#pragma unroll
    for (int g = 0; g < 4; ++g) {
#pragma unroll
        for (int i = 0; i < 3; ++i) {
#pragma unroll
            for (int j = 0; j < 3; ++j) {
                acc[i * 3 + j] += fabsf(e[3 * g + i] - t[3 * g + j]);
            }
        }
    }
}

// --- Kernel 1: per-block partial sums. Branch-free static trip count; two
// 2-chunk load bursts (12 dwordx4 in flight) so vmcnt never drains to 0
// between bursts; VGPR-capped for ~20 waves/CU of residency. ---
__global__ __launch_bounds__(THREADS, 5) void pil_partial(
        const float* __restrict__ est,
        const float* __restrict__ tgt,
        float* __restrict__ ws) {
    const int b   = blockIdx.x / BLOCKS_PER_B;
    const int blk = blockIdx.x % BLOCKS_PER_B;
    const int t   = blk * THREADS + threadIdx.x;  // 0..16383 within b

    const float4* eb = (const float4*)(est + (size_t)b * FLOATS_PER_B);
    const float4* tb = (const float4*)(tgt + (size_t)b * FLOATS_PER_B);

    float acc[9];
#pragma unroll
    for (int k = 0; k < 9; ++k) acc[k] = 0.0f;

    const int c0 = t;
    const int c1 = t + TPB;
    const int c2 = t + 2 * TPB;
    const int c3 = t + 3 * TPB;

    // Burst A: 12 loads in flight.
    const float4 ea0 = eb[3 * c0 + 0], ea1 = eb[3 * c0 + 1], ea2 = eb[3 * c0 + 2];
    const float4 ta0 = tb[3 * c0 + 0], ta1 = tb[3 * c0 + 1], ta2 = tb[3 * c0 + 2];
    const float4 eb0 = eb[3 * c1 + 0], eb1 = eb[3 * c1 + 1], eb2 = eb[3 * c1 + 2];
    const float4 tb0 = tb[3 * c1 + 0], tb1 = tb[3 * c1 + 1], tb2 = tb[3 * c1 + 2];

    acc_chunk(acc, ea0, ea1, ea2, ta0, ta1, ta2);

    // Burst B issued while burst A's second chunk computes.
    const float4 ec0 = eb[3 * c2 + 0], ec1 = eb[3 * c2 + 1], ec2 = eb[3 * c2 + 2];
    const float4 tc0 = tb[3 * c2 + 0], tc1 = tb[3 * c2 + 1], tc2 = tb[3 * c2 + 2];

    acc_chunk(acc, eb0, eb1, eb2, tb0, tb1, tb2);

    const float4 ed0 = eb[3 * c3 + 0], ed1 = eb[3 * c3 + 1], ed2 = eb[3 * c3 + 2];
    const float4 td0 = tb[3 * c3 + 0], td1 = tb[3 * c3 + 1], td2 = tb[3 * c3 + 2];

    acc_chunk(acc, ec0, ec1, ec2, tc0, tc1, tc2);
    acc_chunk(acc, ed0, ed1, ed2, td0, td1, td2);

    // Tail: 128 leftover chunks per b, handled by blk 0 threads 0..127.
    if (t < TAIL) {
        const int c4 = MAIN_CHUNKS + t;
        const float4 x0 = eb[3 * c4 + 0], x1 = eb[3 * c4 + 1], x2 = eb[3 * c4 + 2];
        const float4 y0 = tb[3 * c4 + 0], y1 = tb[3 * c4 + 1], y2 = tb[3 * c4 + 2];
        acc_chunk(acc, x0, x1, x2, y0, y1, y2);
    }

    // Wave-level reduction (64 lanes) of each of the 9 accumulators.
#pragma unroll
    for (int k = 0; k < 9; ++k) {
        float v = acc[k];
#pragma unroll
        for (int off = 32; off > 0; off >>= 1) v += __shfl_down(v, off);
        acc[k] = v;
    }

    __shared__ float sred[THREADS / 64][9];
    const int wave = threadIdx.x >> 6;
    const int lane = threadIdx.x & 63;
    if (lane == 0) {
#pragma unroll
        for (int k = 0; k < 9; ++k) sred[wave][k] = acc[k];
    }
    __syncthreads();
    if (threadIdx.x < 9) {
        float s = 0.0f;
#pragma unroll
        for (int w = 0; w < THREADS / 64; ++w) s += sred[w][threadIdx.x];
        ws[(size_t)(b * BLOCKS_PER_B + blk) * 9 + threadIdx.x] = s;
    }
}

// --- Kernel 2: sum block partials, per-b perm losses, min, mean over b ---
__global__ void pil_finalize(const float* __restrict__ ws, float* __restrict__ out) {
    __shared__ float sC[BB][9];
    const int p = threadIdx.x;  // 320 threads; first 288 sum partials
    if (p < BB * 9) {
        const int b = p / 9, k = p % 9;
        float s = 0.0f;
        for (int blk = 0; blk < BLOCKS_PER_B; ++blk)
            s += ws[(size_t)(b * BLOCKS_PER_B + blk) * 9 + k];
        sC[b][k] = s;
    }
    __syncthreads();

    if (p < 64) {  // wave 0 only
        float loss = 0.0f;
        if (p < BB) {
            float C[3][3];
#pragma unroll
            for (int i = 0; i < 3; ++i)
#pragma unroll
                for (int j = 0; j < 3; ++j)
                    C[i][j] = sC[p][i * 3 + j] * (1.0f / (float)NN);

            const int P[6][3] = {{0, 1, 2}, {0, 2, 1}, {1, 0, 2},
                                 {1, 2, 0}, {2, 0, 1}, {2, 1, 0}};
            float best = 3.4e38f;
#pragma unroll
            for (int q = 0; q < 6; ++q) {
                float l = (C[P[q][0]][0] + C[P[q][1]][1] + C[P[q][2]][2]) *
                          (1.0f / 3.0f);
                best = fminf(best, l);
            }
            loss = best;
        }
#pragma unroll
        for (int off = 32; off > 0; off >>= 1) loss += __shfl_down(loss, off);
        if (p == 0) out[0] = loss * (1.0f / (float)BB);
    }
}

extern "C" void kernel_launch(void* const* d_in, const int* in_sizes, int n_in,
                              void* d_out, int out_size, void* d_ws, size_t ws_size,
                              hipStream_t stream) {
    const float* est = (const float*)d_in[0];
    const float* tgt = (const float*)d_in[1];
    float* ws  = (float*)d_ws;   // 32*64*9 floats = 73728 B of scratch
    float* out = (float*)d_out;

    pil_partial<<<BB * BLOCKS_PER_B, THREADS, 0, stream>>>(est, tgt, ws);
    pil_finalize<<<1, 320, 0, stream>>>(ws, out);
}